// Round 4
// baseline (479.338 us; speedup 1.0000x reference)
//
#include <hip/hip_runtime.h>
#include <stdint.h>

typedef __bf16 bf16x8 __attribute__((ext_vector_type(8)));
typedef float floatx4 __attribute__((ext_vector_type(4)));

#define SB0 __builtin_amdgcn_sched_barrier(0)

__device__ __forceinline__ void gload_lds16(const void* g, void* l) {
    __builtin_amdgcn_global_load_lds((const __attribute__((address_space(1))) void*)g,
                                     (__attribute__((address_space(3))) void*)l, 16, 0, 0);
}

__device__ __forceinline__ uint16_t f2bf(float f) {
    uint32_t u = __float_as_uint(f);
    u += 0x7fff + ((u >> 16) & 1);   // RNE
    return (uint16_t)(u >> 16);
}
__device__ __forceinline__ uint32_t f2bf2(float lo, float hi) {
    return (uint32_t)f2bf(lo) | ((uint32_t)f2bf(hi) << 16);
}

// ---- fused normalize_adj + sparse row gather ------------------------------
struct AmulSM {
    float vv[256];
    int   jj[256];
    float part[4];
    int   wcnt[4];
    int   woff[4];
    float sinv;
    int   n0;
};

__device__ __forceinline__ void amul_body(const float* __restrict__ adj,
                                          const float* __restrict__ H,
                                          uint16_t* __restrict__ outp,
                                          int b, int i, int tid, AmulSM* sm)
{
    const float* A = adj + ((size_t)b << 16);
    float aij = A[(i << 8) + tid];
    float aji = A[(tid << 8) + i];
    float v = fmaxf(aij, aji);
    if (tid == i) v += 1.0f;

    float s = v;
    #pragma unroll
    for (int off = 32; off > 0; off >>= 1) s += __shfl_down(s, off);

    bool pred = v != 0.0f;
    unsigned long long m = __ballot(pred);
    int wid = tid >> 6;
    if ((tid & 63) == 0) { sm->part[wid] = s; sm->wcnt[wid] = (int)__popcll(m); }
    __syncthreads();
    if (tid == 0) {
        float t = sm->part[0] + sm->part[1] + sm->part[2] + sm->part[3];
        sm->sinv = t > 0.0f ? 1.0f / t : 0.0f;
        int o = 0;
        #pragma unroll
        for (int w = 0; w < 4; ++w) { sm->woff[w] = o; o += sm->wcnt[w]; }
        sm->n0 = o;
    }
    __syncthreads();
    if (pred) {
        int pos = sm->woff[wid] + (int)__popcll(m & ((1ull << (tid & 63)) - 1ull));
        sm->vv[pos] = v * sm->sinv;
        sm->jj[pos] = tid;
    }
    __syncthreads();

    const int n0 = sm->n0;
    const int f0 = tid * 8;
    const float* Hb = H + (((size_t)b) << 8) * 2048;
    float acc[8] = {};
    for (int c = 0; c < n0; ++c) {
        float av = sm->vv[c];
        const float* hp = Hb + (size_t)sm->jj[c] * 2048 + f0;
        float4 p = *(const float4*)hp;
        float4 q = *(const float4*)(hp + 4);
        acc[0] += av * p.x; acc[1] += av * p.y; acc[2] += av * p.z; acc[3] += av * p.w;
        acc[4] += av * q.x; acc[5] += av * q.y; acc[6] += av * q.z; acc[7] += av * q.w;
    }
    uint4 o;
    o.x = f2bf2(acc[0], acc[1]);
    o.y = f2bf2(acc[2], acc[3]);
    o.z = f2bf2(acc[4], acc[5]);
    o.w = f2bf2(acc[6], acc[7]);
    *(uint4*)(outp + (((size_t)b << 8) + i) * 2048 + f0) = o;
}

// XCD-swizzled (b,i): XCD x (=bid%8) keeps one batch's H (2MB) L2-resident
__device__ __forceinline__ void amul_swizzle(int bid, int& b, int& i) {
    int x = bid & 7, g = bid >> 3;
    b = x >> 1;
    i = ((x & 1) << 7) + g;
}

// ---- dispatch 1: amul#1 | wT | W1/W2-transpose | pad_x (inputs only) ------
#define PR_AM 1024
#define PR_W  3072
#define PR_T  5120
#define PR_N  17456

__global__ __launch_bounds__(256)
void k_prep(const float* __restrict__ x, uint16_t* __restrict__ xpad,
            const float* __restrict__ w, uint16_t* __restrict__ wT,
            const float* __restrict__ W1, const float* __restrict__ W2,
            uint16_t* __restrict__ W1T, uint16_t* __restrict__ W2T,
            const float* __restrict__ adj, const float* __restrict__ nodes,
            uint16_t* __restrict__ gbf)
{
    __shared__ union {
        float  wbuf[6144];
        float  tile[64][65];
        AmulSM am;
    } sm;
    const int bid = blockIdx.x;
    const int tid = threadIdx.x;

    if (bid < PR_AM) {
        int b, i; amul_swizzle(bid, b, i);
        amul_body(adj, nodes, gbf, b, i, tid, &sm.am);
    } else if (bid < PR_W) {
        // conv_w [o][i][h] -> wT [o][h*2048+i] bf16 (LDS-staged)
        int o = bid - PR_AM;
        const float* src = w + (size_t)o * 6144;
        uint16_t*    dst = wT + (size_t)o * 6144;
        #pragma unroll
        for (int it = 0; it < 24; ++it)
            sm.wbuf[it * 256 + tid] = src[it * 256 + tid];
        __syncthreads();
        #pragma unroll
        for (int h = 0; h < 3; ++h)
            #pragma unroll
            for (int c = 0; c < 8; ++c) {
                int i = c * 256 + tid;
                dst[h * 2048 + i] = f2bf(sm.wbuf[i * 3 + h]);   // stride-3: conflict-free
            }
    } else if (bid < PR_T) {
        // W1/W2 [2048][2048] -> bf16 transpose
        int t  = bid - PR_W;
        int z  = t >> 10;
        int by = (t >> 5) & 31;
        int bx = t & 31;
        const float* src = z ? W2 : W1;
        uint16_t*    dst = z ? W2T : W1T;
        int tx = tid & 63, ty = tid >> 6;
        for (int rr = ty; rr < 64; rr += 4)
            sm.tile[rr][tx] = src[(size_t)(by * 64 + rr) * 2048 + bx * 64 + tx];
        __syncthreads();
        for (int rr = ty; rr < 64; rr += 4)
            dst[(size_t)(bx * 64 + rr) * 2048 + by * 64 + tx] = f2bf(sm.tile[tx][rr]);
    } else {
        // x [12,512,2048] f32 -> xpad [12,514,2048] bf16, 4 elems/thread
        int idx4 = (bid - PR_T) * 256 + tid;       // < 3,158,016
        int ch4  = idx4 & 511;
        int tmp  = idx4 >> 9;                      // b*514 + tt
        int b    = tmp / 514;
        int tt   = tmp - b * 514;
        float4 v = {0.0f, 0.0f, 0.0f, 0.0f};
        if (tt >= 1 && tt <= 512)
            v = *(const float4*)(x + ((size_t)(b * 512 + tt - 1) << 11) + ch4 * 4);
        uint2 o = { f2bf2(v.x, v.y), f2bf2(v.z, v.w) };
        ((uint2*)xpad)[idx4] = o;
    }
}

// ---- 128x128 GEMM tile (m97-class), BK=64, swizzled 64B-row LDS -----------
// lds = 32KB: As 16KB [s][128][32] + Bs 16KB. Conflict-free via r1 swizzle:
// store chunk c: row=(c>>2)&127, slot=c&3, src col = s*32 + (slot^(row&3))*8
// read: byte = s*8192 + row*64 + ((lq*16) ^ ((row&3)<<4))
template<bool RELU>
__device__ __forceinline__ void g128_tile(char* lds, const uint16_t* __restrict__ A,
                                          const uint16_t* __restrict__ BT,
                                          float* __restrict__ C, const float* __restrict__ bias,
                                          int rt, int ct, int tid)
{
    char* As = lds;
    char* Bs = lds + 16384;
    const int lane = tid & 63, wave = tid >> 6;
    const int wm = (wave >> 1) * 64, wn = (wave & 1) * 64;
    const int lm = lane & 15, lq = lane >> 4;
    const int abyte = (wm + lm) * 64 + ((lq * 16) ^ ((lm & 3) << 4));
    const int bbyte = (wn + lm) * 64 + ((lq * 16) ^ ((lm & 3) << 4));

    int soff[4];
    #pragma unroll
    for (int j = 0; j < 4; ++j) {
        int c = tid + 256 * j;                  // 0..1023
        int row = (c >> 2) & 127;
        soff[j] = row * 2048 + ((c >> 9) << 5) + (((c & 3) ^ (row & 3)) << 3);
    }

    floatx4 acc[4][4] = {};
    for (int k0 = 0; k0 < 2048; k0 += 64) {
        #pragma unroll
        for (int j = 0; j < 4; ++j) {
            gload_lds16(A  + (size_t)rt * 2048 + soff[j] + k0, As + tid * 16 + j * 4096);
            gload_lds16(BT + (size_t)ct * 2048 + soff[j] + k0, Bs + tid * 16 + j * 4096);
        }
        __syncthreads();
        #pragma unroll
        for (int s = 0; s < 2; ++s) {
            bf16x8 af[4], bfr[4];
            #pragma unroll
            for (int mt = 0; mt < 4; ++mt)
                af[mt] = *(const bf16x8*)(As + s * 8192 + abyte + mt * 1024);
            #pragma unroll
            for (int nt = 0; nt < 4; ++nt)
                bfr[nt] = *(const bf16x8*)(Bs + s * 8192 + bbyte + nt * 1024);
            #pragma unroll
            for (int mt = 0; mt < 4; ++mt)
                #pragma unroll
                for (int nt = 0; nt < 4; ++nt)
                    acc[mt][nt] = __builtin_amdgcn_mfma_f32_16x16x32_bf16(af[mt], bfr[nt], acc[mt][nt], 0, 0, 0);
        }
        __syncthreads();
    }

    #pragma unroll
    for (int mt = 0; mt < 4; ++mt)
        #pragma unroll
        for (int nt = 0; nt < 4; ++nt) {
            int col = ct + wn + nt * 16 + lm;
            float bv = bias[col];
            #pragma unroll
            for (int r = 0; r < 4; ++r) {
                int row = rt + wm + mt * 16 + lq * 4 + r;
                float v = acc[mt][nt][r] + bv;
                if (RELU) v = fmaxf(v, 0.0f);
                C[(size_t)row * 2048 + col] = v;
            }
        }
}

// ===========================================================================
// conv GEMM: 192x256 tile, 256 thr (4 waves 2x2), per-wave 96x128, BK=32,
// 2-deep LDS (A 2x12KB @0, B 2x16KB @24576 -> 56KB), counted vmcnt(7),
// 2 barriers/window. LDS read demand 61.6 B/cyc < 85 ceiling (was 88).
// 2 blocks/CU co-residency fills stalls.
// ===========================================================================
template<int CUR, bool STG, int VN>
__device__ __forceinline__ void conv_w2(char* smem, int tid,
    const uint16_t* (&aP)[3], const uint16_t* (&bP)[4],
    int abase, int bbase, floatx4 (&acc)[6][8])
{
    char* As  = smem + CUR * 12288;
    char* Bs  = smem + 24576 + CUR * 16384;
    char* Asn = smem + (CUR ^ 1) * 12288;
    char* Bsn = smem + 24576 + (CUR ^ 1) * 16384;

    if constexpr (STG) {
        #pragma unroll
        for (int j = 0; j < 3; ++j) { gload_lds16(aP[j], Asn + tid * 16 + j * 4096); aP[j] += 32; }
        #pragma unroll
        for (int j = 0; j < 4; ++j) { gload_lds16(bP[j], Bsn + tid * 16 + j * 4096); bP[j] += 32; }
    }
    SB0;
    asm volatile("s_waitcnt vmcnt(%0)" :: "i"(VN));
    SB0;
    __builtin_amdgcn_s_barrier();
    SB0;

    bf16x8 bv[8], av[3];
    #pragma unroll
    for (int fn = 0; fn < 8; ++fn) bv[fn] = *(const bf16x8*)(Bs + bbase + fn * 1024);
    #pragma unroll
    for (int fm = 0; fm < 3; ++fm) av[fm] = *(const bf16x8*)(As + abase + fm * 1024);
    __builtin_amdgcn_s_setprio(1);
    #pragma unroll
    for (int fm = 0; fm < 3; ++fm)
        #pragma unroll
        for (int fn = 0; fn < 8; ++fn)
            acc[fm][fn] = __builtin_amdgcn_mfma_f32_16x16x32_bf16(av[fm], bv[fn], acc[fm][fn], 0, 0, 0);
    __builtin_amdgcn_s_setprio(0);
    #pragma unroll
    for (int fm = 0; fm < 3; ++fm) av[fm] = *(const bf16x8*)(As + abase + 3072 + fm * 1024);
    __builtin_amdgcn_s_setprio(1);
    #pragma unroll
    for (int fm = 0; fm < 3; ++fm)
        #pragma unroll
        for (int fn = 0; fn < 8; ++fn)
            acc[3 + fm][fn] = __builtin_amdgcn_mfma_f32_16x16x32_bf16(av[fm], bv[fn], acc[3 + fm][fn], 0, 0, 0);
    __builtin_amdgcn_s_setprio(0);
    SB0;
    __builtin_amdgcn_s_barrier();
    SB0;
}

// ---- dispatch 2: conv GEMM (256 blocks) || gemm128#1 (128 blocks) ---------
__global__ __launch_bounds__(256, 2)
void k_big(const uint16_t* __restrict__ xpad, const uint16_t* __restrict__ wmT,
           float* __restrict__ feats, const float* __restrict__ conv_b,
           const uint16_t* __restrict__ gbf, const uint16_t* __restrict__ W1T,
           float* __restrict__ h, const float* __restrict__ b1)
{
    __shared__ __align__(16) char smem[57344];
    const int bid = blockIdx.x;
    const int tid = threadIdx.x;

    if (bid < 256) {
        // -------- conv: 192x256 tile, XCD-swizzled (256 % 8 == 0) ----------
        const int xcd  = bid & 7;
        const int gg   = bid >> 3;                 // 0..31
        const int tile = xcd * 32 + gg;
        const int rt   = (tile >> 3) * 192;        // 0..5952
        const int ct   = (tile & 7) * 256;         // 0..1792

        const int lane = tid & 63, wave = tid >> 6;
        const int mw = wave >> 1, nw = wave & 1;
        const int lm = lane & 15, lq = lane >> 4;
        const int abase = (mw * 96 + lm) * 64 + ((lq * 16) ^ ((lm & 3) << 4));
        const int bbase = (nw * 128 + lm) * 64 + ((lq * 16) ^ ((lm & 3) << 4));

        // staging sources: A chunk c=tid+256j (j<3): row=c>>2 (0..191),
        // slot=c&3, src col=(slot^(row&3))*8; xpad addr = rowbase + k (linear)
        const uint16_t* aP[3];
        const uint16_t* bP[4];
        #pragma unroll
        for (int j = 0; j < 3; ++j) {
            int c = tid + 256 * j;
            int row = c >> 2;
            int R = rt + row;
            aP[j] = xpad + (((size_t)((R >> 9) * 514 + (R & 511))) << 11)
                         + (((c & 3) ^ (row & 3)) << 3);
        }
        #pragma unroll
        for (int j = 0; j < 4; ++j) {
            int c = tid + 256 * j;
            int row = c >> 2;
            bP[j] = wmT + (size_t)(ct + row) * 6144 + (((c & 3) ^ (row & 3)) << 3);
        }

        // prologue: stage K-tile 0 into buf 0
        #pragma unroll
        for (int j = 0; j < 3; ++j) { gload_lds16(aP[j], smem + tid * 16 + j * 4096); aP[j] += 32; }
        #pragma unroll
        for (int j = 0; j < 4; ++j) { gload_lds16(bP[j], smem + 24576 + tid * 16 + j * 4096); bP[j] += 32; }

        floatx4 acc[6][8] = {};
        // 192 windows: 95x2 staged + t=190 staged + t=191 drain
        #pragma unroll 1
        for (int it = 0; it < 95; ++it) {
            conv_w2<0, true, 7>(smem, tid, aP, bP, abase, bbase, acc);
            conv_w2<1, true, 7>(smem, tid, aP, bP, abase, bbase, acc);
        }
        conv_w2<0, true, 7>(smem, tid, aP, bP, abase, bbase, acc);
        conv_w2<1, false, 0>(smem, tid, aP, bP, abase, bbase, acc);

        // C write: frag layout col=lane&15, row=(lane>>4)*4+r
        #pragma unroll
        for (int fm = 0; fm < 6; ++fm)
            #pragma unroll
            for (int fn = 0; fn < 8; ++fn) {
                int col = ct + nw * 128 + fn * 16 + lm;
                float bb = conv_b[col];
                #pragma unroll
                for (int r = 0; r < 4; ++r) {
                    int row = rt + mw * 96 + fm * 16 + lq * 4 + r;
                    feats[(size_t)row * 2048 + col] = fmaxf(acc[fm][fn][r] + bb, 0.0f);
                }
            }
    } else {
        // -------- gemm128#1: h = relu(gbf @ W1T^T + b1), M=1024 N=2048 -----
        const int t   = bid - 256;                 // 0..127
        const int idx = (t & 7) * 16 + (t >> 3);   // XCD swizzle
        const int rt  = (idx & 7) * 128;
        const int ct  = (idx >> 3) * 128;
        g128_tile<true>(smem, gbf, W1T, h, b1, rt, ct, tid);
    }
}

// ---- dispatch 3: ahb = a @ h (bf16), normalize folded in, XCD-swizzled ----
__global__ __launch_bounds__(256)
void k_amul(const float* __restrict__ adj, const float* __restrict__ H,
            uint16_t* __restrict__ outp)
{
    __shared__ AmulSM sm;
    int b, i; amul_swizzle(blockIdx.x, b, i);
    amul_body(adj, H, outp, b, i, threadIdx.x, &sm);
}

// ---- dispatch 4: out = ahb @ W2T^T + b2, 128x128 tiles, XCD-swizzled ------
__global__ __launch_bounds__(256)
void k_gemm64(const uint16_t* __restrict__ A, const uint16_t* __restrict__ BT,
              float* __restrict__ C, const float* __restrict__ bias)
{
    __shared__ __align__(16) char lds[32768];
    const int bid = blockIdx.x;                    // 0..127
    const int idx = (bid & 7) * 16 + (bid >> 3);
    const int rt  = (idx & 7) * 128;
    const int ct  = (idx >> 3) * 128;
    g128_tile<false>(lds, A, BT, C, bias, rt, ct, threadIdx.x);
}

// ---- launch ---------------------------------------------------------------

extern "C" void kernel_launch(void* const* d_in, const int* in_sizes, int n_in,
                              void* d_out, int out_size, void* d_ws, size_t ws_size,
                              hipStream_t stream)
{
    const float* x      = (const float*)d_in[0];
    const float* nodes  = (const float*)d_in[1];
    const float* adj    = (const float*)d_in[2];
    const float* conv_w = (const float*)d_in[3];
    const float* conv_b = (const float*)d_in[4];
    const float* W1     = (const float*)d_in[5];
    const float* b1     = (const float*)d_in[6];
    const float* W2     = (const float*)d_in[7];
    const float* b2     = (const float*)d_in[8];
    float* out = (float*)d_out;

    char* ws = (char*)d_ws;
    uint16_t* xpad   = (uint16_t*)(ws);                 // 25,288,704
    uint16_t* wmT    = (uint16_t*)(ws + 25288704);      // 25,165,824
    uint16_t* W1T    = (uint16_t*)(ws + 50454528);      // 8,388,608
    uint16_t* W2T    = (uint16_t*)(ws + 58843136);      // 8,388,608
    uint16_t* gbf    = (uint16_t*)(ws + 67231744);      // 4,194,304  a@nodes (bf16)
    float*    h      = (float*)   (ws + 71426048);      // 8,388,608  relu(gbf@W1+b1)
    uint16_t* ahb    = (uint16_t*)(ws + 79814656);      // 4,194,304  a@h (bf16)

    // d1: everything that depends only on inputs
    k_prep<<<PR_N, 256, 0, stream>>>(x, xpad, conv_w, wmT,
                                     W1, W2, W1T, W2T, adj, nodes, gbf);
    // d2: conv GEMM (96x128/wave, 2 blocks/CU) || gemm128#1 co-resident
    k_big<<<384, 256, 0, stream>>>(xpad, wmT, out, conv_b, gbf, W1T, h, b1);
    // d3: ahb = a @ h
    k_amul<<<1024, 256, 0, stream>>>(adj, h, ahb);
    // d4: out_gcn = ahb @ W2 + b2
    k_gemm64<<<128, 256, 0, stream>>>(ahb, W2T, out + 12582912, b2);
}

// Round 5
// 436.448 us; speedup vs baseline: 1.0983x; 1.0983x over previous
//
#include <hip/hip_runtime.h>
#include <stdint.h>

typedef __bf16 bf16x8 __attribute__((ext_vector_type(8)));
typedef float floatx4 __attribute__((ext_vector_type(4)));

#define SB0 __builtin_amdgcn_sched_barrier(0)

__device__ __forceinline__ void gload_lds16(const void* g, void* l) {
    __builtin_amdgcn_global_load_lds((const __attribute__((address_space(1))) void*)g,
                                     (__attribute__((address_space(3))) void*)l, 16, 0, 0);
}

__device__ __forceinline__ uint16_t f2bf(float f) {
    uint32_t u = __float_as_uint(f);
    u += 0x7fff + ((u >> 16) & 1);   // RNE
    return (uint16_t)(u >> 16);
}
__device__ __forceinline__ uint32_t f2bf2(float lo, float hi) {
    return (uint32_t)f2bf(lo) | ((uint32_t)f2bf(hi) << 16);
}

// ---- fused normalize_adj + sparse row gather ------------------------------
struct AmulSM {
    float vv[256];
    int   jj[256];
    float part[4];
    int   wcnt[4];
    int   woff[4];
    float sinv;
    int   n0;
};

__device__ __forceinline__ void amul_body(const float* __restrict__ adj,
                                          const float* __restrict__ H,
                                          uint16_t* __restrict__ outp,
                                          int b, int i, int tid, AmulSM* sm)
{
    const float* A = adj + ((size_t)b << 16);
    float aij = A[(i << 8) + tid];
    float aji = A[(tid << 8) + i];
    float v = fmaxf(aij, aji);
    if (tid == i) v += 1.0f;

    float s = v;
    #pragma unroll
    for (int off = 32; off > 0; off >>= 1) s += __shfl_down(s, off);

    bool pred = v != 0.0f;
    unsigned long long m = __ballot(pred);
    int wid = tid >> 6;
    if ((tid & 63) == 0) { sm->part[wid] = s; sm->wcnt[wid] = (int)__popcll(m); }
    __syncthreads();
    if (tid == 0) {
        float t = sm->part[0] + sm->part[1] + sm->part[2] + sm->part[3];
        sm->sinv = t > 0.0f ? 1.0f / t : 0.0f;
        int o = 0;
        #pragma unroll
        for (int w = 0; w < 4; ++w) { sm->woff[w] = o; o += sm->wcnt[w]; }
        sm->n0 = o;
    }
    __syncthreads();
    if (pred) {
        int pos = sm->woff[wid] + (int)__popcll(m & ((1ull << (tid & 63)) - 1ull));
        sm->vv[pos] = v * sm->sinv;
        sm->jj[pos] = tid;
    }
    __syncthreads();

    const int n0 = sm->n0;
    const int f0 = tid * 8;
    const float* Hb = H + (((size_t)b) << 8) * 2048;
    float acc[8] = {};
    for (int c = 0; c < n0; ++c) {
        float av = sm->vv[c];
        const float* hp = Hb + (size_t)sm->jj[c] * 2048 + f0;
        float4 p = *(const float4*)hp;
        float4 q = *(const float4*)(hp + 4);
        acc[0] += av * p.x; acc[1] += av * p.y; acc[2] += av * p.z; acc[3] += av * p.w;
        acc[4] += av * q.x; acc[5] += av * q.y; acc[6] += av * q.z; acc[7] += av * q.w;
    }
    uint4 o;
    o.x = f2bf2(acc[0], acc[1]);
    o.y = f2bf2(acc[2], acc[3]);
    o.z = f2bf2(acc[4], acc[5]);
    o.w = f2bf2(acc[6], acc[7]);
    *(uint4*)(outp + (((size_t)b << 8) + i) * 2048 + f0) = o;
}

// XCD-swizzled (b,i): XCD x (=bid%8) keeps one batch's H (2MB) L2-resident
__device__ __forceinline__ void amul_swizzle(int bid, int& b, int& i) {
    int x = bid & 7, g = bid >> 3;
    b = x >> 1;
    i = ((x & 1) << 7) + g;
}

// ---- dispatch 1: amul#1 | wT | W1/W2-transpose | pad_x (inputs only) ------
#define PR_AM 1024
#define PR_W  3072
#define PR_T  5120
#define PR_N  17456

__global__ __launch_bounds__(256)
void k_prep(const float* __restrict__ x, uint16_t* __restrict__ xpad,
            const float* __restrict__ w, uint16_t* __restrict__ wT,
            const float* __restrict__ W1, const float* __restrict__ W2,
            uint16_t* __restrict__ W1T, uint16_t* __restrict__ W2T,
            const float* __restrict__ adj, const float* __restrict__ nodes,
            uint16_t* __restrict__ gbf)
{
    __shared__ union {
        float  wbuf[6144];
        float  tile[64][65];
        AmulSM am;
    } sm;
    const int bid = blockIdx.x;
    const int tid = threadIdx.x;

    if (bid < PR_AM) {
        int b, i; amul_swizzle(bid, b, i);
        amul_body(adj, nodes, gbf, b, i, tid, &sm.am);
    } else if (bid < PR_W) {
        // conv_w [o][i][h] -> wT [o][h*2048+i] bf16 (LDS-staged)
        int o = bid - PR_AM;
        const float* src = w + (size_t)o * 6144;
        uint16_t*    dst = wT + (size_t)o * 6144;
        #pragma unroll
        for (int it = 0; it < 24; ++it)
            sm.wbuf[it * 256 + tid] = src[it * 256 + tid];
        __syncthreads();
        #pragma unroll
        for (int h = 0; h < 3; ++h)
            #pragma unroll
            for (int c = 0; c < 8; ++c) {
                int i = c * 256 + tid;
                dst[h * 2048 + i] = f2bf(sm.wbuf[i * 3 + h]);   // stride-3: conflict-free
            }
    } else if (bid < PR_T) {
        // W1/W2 [2048][2048] -> bf16 transpose
        int t  = bid - PR_W;
        int z  = t >> 10;
        int by = (t >> 5) & 31;
        int bx = t & 31;
        const float* src = z ? W2 : W1;
        uint16_t*    dst = z ? W2T : W1T;
        int tx = tid & 63, ty = tid >> 6;
        for (int rr = ty; rr < 64; rr += 4)
            sm.tile[rr][tx] = src[(size_t)(by * 64 + rr) * 2048 + bx * 64 + tx];
        __syncthreads();
        for (int rr = ty; rr < 64; rr += 4)
            dst[(size_t)(bx * 64 + rr) * 2048 + by * 64 + tx] = f2bf(sm.tile[tx][rr]);
    } else {
        // x [12,512,2048] f32 -> xpad [12,514,2048] bf16, 4 elems/thread
        int idx4 = (bid - PR_T) * 256 + tid;       // < 3,158,016
        int ch4  = idx4 & 511;
        int tmp  = idx4 >> 9;                      // b*514 + tt
        int b    = tmp / 514;
        int tt   = tmp - b * 514;
        float4 v = {0.0f, 0.0f, 0.0f, 0.0f};
        if (tt >= 1 && tt <= 512)
            v = *(const float4*)(x + ((size_t)(b * 512 + tt - 1) << 11) + ch4 * 4);
        uint2 o = { f2bf2(v.x, v.y), f2bf2(v.z, v.w) };
        ((uint2*)xpad)[idx4] = o;
    }
}

// ---- 128x128 GEMM tile (m97-class), BK=64, swizzled 64B-row LDS -----------
// (verified round 4) store chunk c: row=(c>>2)&127, col=(c&3 ^ row&3)*8+(c>>9)*32
// read: byte = s*8192 + row*64 + ((lq*16) ^ ((row&3)<<4))
template<bool RELU>
__device__ __forceinline__ void g128_tile(char* lds, const uint16_t* __restrict__ A,
                                          const uint16_t* __restrict__ BT,
                                          float* __restrict__ C, const float* __restrict__ bias,
                                          int rt, int ct, int tid)
{
    char* As = lds;
    char* Bs = lds + 16384;
    const int lane = tid & 63, wave = tid >> 6;
    const int wm = (wave >> 1) * 64, wn = (wave & 1) * 64;
    const int lm = lane & 15, lq = lane >> 4;
    const int abyte = (wm + lm) * 64 + ((lq * 16) ^ ((lm & 3) << 4));
    const int bbyte = (wn + lm) * 64 + ((lq * 16) ^ ((lm & 3) << 4));

    int soff[4];
    #pragma unroll
    for (int j = 0; j < 4; ++j) {
        int c = tid + 256 * j;                  // 0..1023
        int row = (c >> 2) & 127;
        soff[j] = row * 2048 + ((c >> 9) << 5) + (((c & 3) ^ (row & 3)) << 3);
    }

    floatx4 acc[4][4] = {};
    for (int k0 = 0; k0 < 2048; k0 += 64) {
        #pragma unroll
        for (int j = 0; j < 4; ++j) {
            gload_lds16(A  + (size_t)rt * 2048 + soff[j] + k0, As + tid * 16 + j * 4096);
            gload_lds16(BT + (size_t)ct * 2048 + soff[j] + k0, Bs + tid * 16 + j * 4096);
        }
        __syncthreads();
        #pragma unroll
        for (int s = 0; s < 2; ++s) {
            bf16x8 af[4], bfr[4];
            #pragma unroll
            for (int mt = 0; mt < 4; ++mt)
                af[mt] = *(const bf16x8*)(As + s * 8192 + abyte + mt * 1024);
            #pragma unroll
            for (int nt = 0; nt < 4; ++nt)
                bfr[nt] = *(const bf16x8*)(Bs + s * 8192 + bbyte + nt * 1024);
            #pragma unroll
            for (int mt = 0; mt < 4; ++mt)
                #pragma unroll
                for (int nt = 0; nt < 4; ++nt)
                    acc[mt][nt] = __builtin_amdgcn_mfma_f32_16x16x32_bf16(af[mt], bfr[nt], acc[mt][nt], 0, 0, 0);
        }
        __syncthreads();
    }

    #pragma unroll
    for (int mt = 0; mt < 4; ++mt)
        #pragma unroll
        for (int nt = 0; nt < 4; ++nt) {
            int col = ct + wn + nt * 16 + lm;
            float bv = bias[col];
            #pragma unroll
            for (int r = 0; r < 4; ++r) {
                int row = rt + wm + mt * 16 + lq * 4 + r;
                float v = acc[mt][nt][r] + bv;
                if (RELU) v = fmaxf(v, 0.0f);
                C[(size_t)row * 2048 + col] = v;
            }
        }
}

// ===========================================================================
// conv GEMM — m201 geometry: BM=BN=256, BK=64, 512 thr (8 waves 2Mx4N),
// per-wave 128x64 (acc[8][4]), 4 phases/K-tile of 16 MFMA each.
// LDS 128KB: per matrix a ring of 4 k-half slots (256 rows x 32k x 2B = 16KB).
// K-tile t uses A/B slots (2t)&3 (s0) and (2t+1)&3 (s1).
// Stage: tile t issues t+1's units: ph0 -> {Bs0 j0,j1, As0 j0,j1},
// ph1 -> {Bs1, As1}. Waits: vmcnt(8) @ph1-close (certifies t's s1, issued one
// tile ago), vmcnt(4) @ph3-close (certifies t+1's s0). In-flight >= 4 always.
// Swizzle (verified r1): phys col ^= ((row&3)<<4); inverse applied on the
// per-thread GLOBAL source column (both-sides rule).
// ===========================================================================
template<int PAR, bool STG, int VN2, bool W1>
__device__ __forceinline__ void conv_tile(char* smem, int tid,
    const uint16_t* (&aS)[2], const uint16_t* (&bS)[2],
    int aro, int bro, floatx4 (&acc)[8][4])
{
    char* A0 = smem + (PAR * 2) * 16384;
    char* A1 = smem + (PAR * 2 + 1) * 16384;
    char* B0 = smem + 65536 + (PAR * 2) * 16384;
    char* B1 = smem + 65536 + (PAR * 2 + 1) * 16384;
    char* An0 = smem + ((PAR ^ 1) * 2) * 16384;
    char* An1 = smem + ((PAR ^ 1) * 2 + 1) * 16384;
    char* Bn0 = smem + 65536 + ((PAR ^ 1) * 2) * 16384;
    char* Bn1 = smem + 65536 + ((PAR ^ 1) * 2 + 1) * 16384;

    bf16x8 av[4], bv[4];

    // -------- ph0: s0, m-quadrant 0 (acc[0..3]) ----------------------------
    #pragma unroll
    for (int nt = 0; nt < 4; ++nt) bv[nt] = *(const bf16x8*)(B0 + bro + nt * 1024);
    #pragma unroll
    for (int mt = 0; mt < 4; ++mt) av[mt] = *(const bf16x8*)(A0 + aro + mt * 1024);
    if constexpr (STG) {
        gload_lds16(bS[0], Bn0 + tid * 16);
        gload_lds16(bS[1], Bn0 + 8192 + tid * 16);
        gload_lds16(aS[0], An0 + tid * 16);
        gload_lds16(aS[1], An0 + 8192 + tid * 16);
    }
    SB0; __builtin_amdgcn_s_barrier();
    asm volatile("s_waitcnt lgkmcnt(0)"); SB0;
    __builtin_amdgcn_s_setprio(1);
    #pragma unroll
    for (int mt = 0; mt < 4; ++mt)
        #pragma unroll
        for (int nt = 0; nt < 4; ++nt)
            acc[mt][nt] = __builtin_amdgcn_mfma_f32_16x16x32_bf16(av[mt], bv[nt], acc[mt][nt], 0, 0, 0);
    __builtin_amdgcn_s_setprio(0);
    SB0; __builtin_amdgcn_s_barrier(); SB0;

    // -------- ph1: s0, m-quadrant 1 (acc[4..7]) ----------------------------
    #pragma unroll
    for (int mt = 0; mt < 4; ++mt) av[mt] = *(const bf16x8*)(A0 + aro + 4096 + mt * 1024);
    if constexpr (STG) {
        gload_lds16(bS[0] + 32, Bn1 + tid * 16);
        gload_lds16(bS[1] + 32, Bn1 + 8192 + tid * 16);
        gload_lds16(aS[0] + 32, An1 + tid * 16);
        gload_lds16(aS[1] + 32, An1 + 8192 + tid * 16);
        aS[0] += 64; aS[1] += 64; bS[0] += 64; bS[1] += 64;
    }
    SB0; __builtin_amdgcn_s_barrier();
    asm volatile("s_waitcnt lgkmcnt(0)"); SB0;
    __builtin_amdgcn_s_setprio(1);
    #pragma unroll
    for (int mt = 0; mt < 4; ++mt)
        #pragma unroll
        for (int nt = 0; nt < 4; ++nt)
            acc[4 + mt][nt] = __builtin_amdgcn_mfma_f32_16x16x32_bf16(av[mt], bv[nt], acc[4 + mt][nt], 0, 0, 0);
    __builtin_amdgcn_s_setprio(0);
    asm volatile("s_waitcnt vmcnt(%0)" :: "i"(VN2));
    SB0; __builtin_amdgcn_s_barrier(); SB0;

    // -------- ph2: s1, m-quadrant 0 ----------------------------------------
    #pragma unroll
    for (int nt = 0; nt < 4; ++nt) bv[nt] = *(const bf16x8*)(B1 + bro + nt * 1024);
    #pragma unroll
    for (int mt = 0; mt < 4; ++mt) av[mt] = *(const bf16x8*)(A1 + aro + mt * 1024);
    SB0; __builtin_amdgcn_s_barrier();
    asm volatile("s_waitcnt lgkmcnt(0)"); SB0;
    __builtin_amdgcn_s_setprio(1);
    #pragma unroll
    for (int mt = 0; mt < 4; ++mt)
        #pragma unroll
        for (int nt = 0; nt < 4; ++nt)
            acc[mt][nt] = __builtin_amdgcn_mfma_f32_16x16x32_bf16(av[mt], bv[nt], acc[mt][nt], 0, 0, 0);
    __builtin_amdgcn_s_setprio(0);
    SB0; __builtin_amdgcn_s_barrier(); SB0;

    // -------- ph3: s1, m-quadrant 1 ----------------------------------------
    #pragma unroll
    for (int mt = 0; mt < 4; ++mt) av[mt] = *(const bf16x8*)(A1 + aro + 4096 + mt * 1024);
    SB0; __builtin_amdgcn_s_barrier();
    asm volatile("s_waitcnt lgkmcnt(0)"); SB0;
    __builtin_amdgcn_s_setprio(1);
    #pragma unroll
    for (int mt = 0; mt < 4; ++mt)
        #pragma unroll
        for (int nt = 0; nt < 4; ++nt)
            acc[4 + mt][nt] = __builtin_amdgcn_mfma_f32_16x16x32_bf16(av[mt], bv[nt], acc[4 + mt][nt], 0, 0, 0);
    __builtin_amdgcn_s_setprio(0);
    if constexpr (W1) asm volatile("s_waitcnt vmcnt(4)");
    SB0; __builtin_amdgcn_s_barrier(); SB0;
}

// ---- dispatch 2: conv GEMM (192 blocks) || gemm128#1 (64 blocks x 2) ------
__global__ __launch_bounds__(512, 2)
void k_big(const uint16_t* __restrict__ xpad, const uint16_t* __restrict__ wmT,
           float* __restrict__ feats, const float* __restrict__ conv_b,
           const uint16_t* __restrict__ gbf, const uint16_t* __restrict__ W1T,
           float* __restrict__ h, const float* __restrict__ b1)
{
    __shared__ __align__(16) char smem[131072];
    const int bid = blockIdx.x;
    const int tid = threadIdx.x;

    if (bid < 192) {
        // -------- conv: 256x256 tile; each XCD owns one N-panel ------------
        const int xcd = bid & 7;
        const int g   = bid >> 3;                  // 0..23
        const int rt  = g * 256;
        const int ct  = xcd * 256;

        const int lane = tid & 63, wave = tid >> 6;
        const int mw = wave >> 2, nw = wave & 3;
        const int lm = lane & 15, lq = lane >> 4;
        const int rxor = (lq * 16) ^ ((lm & 3) << 4);
        const int aro = (mw * 128 + lm) * 64 + rxor;
        const int bro = (nw * 64 + lm) * 64 + rxor;

        // per-thread stage sources: chunk c = j*512+tid -> row c>>2,
        // src col elems = ((c&3)^(row&3))*8 (inverse swizzle); addr linear in k
        const uint16_t* aS[2];
        const uint16_t* bS[2];
        const int srow = tid >> 2;
        const int scol = ((tid & 3) ^ (srow & 3)) << 3;
        #pragma unroll
        for (int j = 0; j < 2; ++j) {
            int R = rt + j * 128 + srow;
            aS[j] = xpad + (((size_t)((R >> 9) * 514 + (R & 511))) << 11) + scol;
            bS[j] = wmT + (size_t)(ct + j * 128 + srow) * 6144 + scol;
        }

        // prologue: stage tile 0 (slots 0,1 both matrices); certify s0 units
        gload_lds16(bS[0], smem + 65536 + tid * 16);
        gload_lds16(bS[1], smem + 65536 + 8192 + tid * 16);
        gload_lds16(aS[0], smem + tid * 16);
        gload_lds16(aS[1], smem + 8192 + tid * 16);
        gload_lds16(bS[0] + 32, smem + 65536 + 16384 + tid * 16);
        gload_lds16(bS[1] + 32, smem + 65536 + 16384 + 8192 + tid * 16);
        gload_lds16(aS[0] + 32, smem + 16384 + tid * 16);
        gload_lds16(aS[1] + 32, smem + 16384 + 8192 + tid * 16);
        aS[0] += 64; aS[1] += 64; bS[0] += 64; bS[1] += 64;
        asm volatile("s_waitcnt vmcnt(4)");
        SB0; __builtin_amdgcn_s_barrier(); SB0;

        floatx4 acc[8][4] = {};
        // 96 K-tiles: t=0..93 in pairs, then 94 (stages 95), then 95 (drain)
        #pragma unroll 1
        for (int it = 0; it < 47; ++it) {
            conv_tile<0, true, 8, true>(smem, tid, aS, bS, aro, bro, acc);
            conv_tile<1, true, 8, true>(smem, tid, aS, bS, aro, bro, acc);
        }
        conv_tile<0, true, 8, true >(smem, tid, aS, bS, aro, bro, acc);   // t=94
        conv_tile<1, false, 0, false>(smem, tid, aS, bS, aro, bro, acc);  // t=95

        // C write: frag layout col=lane&15, row=(lane>>4)*4+r
        #pragma unroll
        for (int mt = 0; mt < 8; ++mt)
            #pragma unroll
            for (int nt = 0; nt < 4; ++nt) {
                int col = ct + nw * 64 + nt * 16 + lm;
                float bb = conv_b[col];
                #pragma unroll
                for (int r = 0; r < 4; ++r) {
                    int row = rt + mw * 128 + mt * 16 + lq * 4 + r;
                    feats[(size_t)row * 2048 + col] = fmaxf(acc[mt][nt][r] + bb, 0.0f);
                }
            }
    } else {
        // -------- gemm128#1: h = relu(gbf @ W1T^T + b1), 2 tiles/block -----
        const int t    = bid - 192;            // 0..63
        const int half = tid >> 8;
        const int st   = t * 2 + half;         // 0..127
        const int idx  = (st & 7) * 16 + (st >> 3);   // XCD swizzle
        const int rt   = (idx & 7) * 128;      // M=1024
        const int ct   = (idx >> 3) * 128;     // N=2048
        g128_tile<true>(smem + half * 32768, gbf, W1T, h, b1, rt, ct, tid & 255);
    }
}

// ---- dispatch 3: ahb = a @ h (bf16), normalize folded in, XCD-swizzled ----
__global__ __launch_bounds__(256)
void k_amul(const float* __restrict__ adj, const float* __restrict__ H,
            uint16_t* __restrict__ outp)
{
    __shared__ AmulSM sm;
    int b, i; amul_swizzle(blockIdx.x, b, i);
    amul_body(adj, H, outp, b, i, threadIdx.x, &sm);
}

// ---- dispatch 4: out = ahb @ W2T^T + b2, 128x128 tiles, XCD-swizzled ------
__global__ __launch_bounds__(256)
void k_gemm64(const uint16_t* __restrict__ A, const uint16_t* __restrict__ BT,
              float* __restrict__ C, const float* __restrict__ bias)
{
    __shared__ __align__(16) char lds[32768];
    const int bid = blockIdx.x;                    // 0..127
    const int idx = (bid & 7) * 16 + (bid >> 3);
    const int rt  = (idx & 7) * 128;
    const int ct  = (idx >> 3) * 128;
    g128_tile<false>(lds, A, BT, C, bias, rt, ct, threadIdx.x);
}

// ---- launch ---------------------------------------------------------------

extern "C" void kernel_launch(void* const* d_in, const int* in_sizes, int n_in,
                              void* d_out, int out_size, void* d_ws, size_t ws_size,
                              hipStream_t stream)
{
    const float* x      = (const float*)d_in[0];
    const float* nodes  = (const float*)d_in[1];
    const float* adj    = (const float*)d_in[2];
    const float* conv_w = (const float*)d_in[3];
    const float* conv_b = (const float*)d_in[4];
    const float* W1     = (const float*)d_in[5];
    const float* b1     = (const float*)d_in[6];
    const float* W2     = (const float*)d_in[7];
    const float* b2     = (const float*)d_in[8];
    float* out = (float*)d_out;

    char* ws = (char*)d_ws;
    uint16_t* xpad   = (uint16_t*)(ws);                 // 25,288,704
    uint16_t* wmT    = (uint16_t*)(ws + 25288704);      // 25,165,824
    uint16_t* W1T    = (uint16_t*)(ws + 50454528);      // 8,388,608
    uint16_t* W2T    = (uint16_t*)(ws + 58843136);      // 8,388,608
    uint16_t* gbf    = (uint16_t*)(ws + 67231744);      // 4,194,304  a@nodes (bf16)
    float*    h      = (float*)   (ws + 71426048);      // 8,388,608  relu(gbf@W1+b1)
    uint16_t* ahb    = (uint16_t*)(ws + 79814656);      // 4,194,304  a@h (bf16)

    // d1: everything that depends only on inputs
    k_prep<<<PR_N, 256, 0, stream>>>(x, xpad, conv_w, wmT,
                                     W1, W2, W1T, W2T, adj, nodes, gbf);
    // d2: conv GEMM (m201-geometry 256^2) || gemm128#1 on remaining CUs
    k_big<<<256, 512, 0, stream>>>(xpad, wmT, out, conv_b, gbf, W1T, h, b1);
    // d3: ahb = a @ h
    k_amul<<<1024, 256, 0, stream>>>(adj, h, ahb);
    // d4: out_gcn = ahb @ W2 + b2
    k_gemm64<<<128, 256, 0, stream>>>(ahb, W2T, out + 12582912, b2);
}